// Round 6
// baseline (66.524 us; speedup 1.0000x reference)
//
#include <hip/hip_runtime.h>

#define GAMMA 0.999f
#define LAMBD 0.7f
#define ALPHA 0.99f

constexpr int A_DIM = 64;
constexpr int CH    = 128;   // rows per block; nch = T/CH = 2048
constexpr int BLK   = 128;   // 2 waves per block

// ---------------------------------------------------------------------------
// K1: one 128-thread block per 128-row chunk.
//  A: per-thread staging of a/r/done + scattered gathers q/pi/mu at action.
//  B: dots. Wave w owns rows [w*64,(w+1)*64); 4 rows per step (sub=lane>>4,
//     li=lane&15, float4/lane), 2 steps interleaved for ILP; 16-lane
//     butterflies -> v_t, v_tp1; coalesced float4 advantages write.
//  C: thread tid owns row tid. Affine F=(Fa,Fb); wave-shuffle suffix scan
//     (no barriers) + 1-barrier cross-wave combine. Emit comb[t]={U,W} with
//     targets[t] = U + W*ye(chunk), and cab[chunk].
// ---------------------------------------------------------------------------
__global__ __launch_bounds__(BLK, 8)
void k_main(const float* __restrict__ q, const float* __restrict__ q_tar,
            const float* __restrict__ pi, const int* __restrict__ a_t,
            const float* __restrict__ r_t, const float* __restrict__ mu_t,
            const int* __restrict__ done_t,
            float* __restrict__ adv_out,
            float2* __restrict__ comb, float2* __restrict__ cab)
{
    __shared__ float sQa[CH], sRho[CH], sKm[CH], sRt[CH];
    __shared__ float sV[CH], sVp[CH];
    __shared__ float sWA[2], sWB[2];

    const int tid  = threadIdx.x;
    const int wave = tid >> 6, lane = tid & 63;
    const int sub  = lane >> 4, li = lane & 15;
    const int R0   = blockIdx.x * CH;

    // ---- phase A: staging + action gathers
    {
        int r = R0 + tid;
        int a = a_t[r];
        sRt[tid] = r_t[r];
        sKm[tid] = 1.0f - (float)done_t[r];
        float qa = q[r * A_DIM + a];
        float pa = pi[r * A_DIM + a];
        float ma = mu_t[r * A_DIM + a];
        sQa[tid]  = qa;
        sRho[tid] = pa / ma;
    }

    // ---- phase B: dots + advantages
    #pragma unroll 2
    for (int i = 0; i < 8; ++i) {
        int lrowA = wave * 64 + i * 8 + sub;
        int lrowB = lrowA + 4;
        int gA = (R0 + lrowA) * A_DIM + li * 4;
        int gB = (R0 + lrowB) * A_DIM + li * 4;

        float4 piA  = *(const float4*)&pi[gA];
        float4 qA   = *(const float4*)&q[gA];
        float4 pipA = *(const float4*)&pi[gA + A_DIM];
        float4 qpA  = *(const float4*)&q_tar[gA + A_DIM];
        float4 piB  = *(const float4*)&pi[gB];
        float4 qB   = *(const float4*)&q[gB];
        float4 pipB = *(const float4*)&pi[gB + A_DIM];
        float4 qpB  = *(const float4*)&q_tar[gB + A_DIM];

        float s0A = piA.x*qA.x + piA.y*qA.y + piA.z*qA.z + piA.w*qA.w;
        float s1A = pipA.x*qpA.x + pipA.y*qpA.y + pipA.z*qpA.z + pipA.w*qpA.w;
        float s0B = piB.x*qB.x + piB.y*qB.y + piB.z*qB.z + piB.w*qB.w;
        float s1B = pipB.x*qpB.x + pipB.y*qpB.y + pipB.z*qpB.z + pipB.w*qpB.w;
        #pragma unroll
        for (int off = 1; off < 16; off <<= 1) {
            s0A += __shfl_xor(s0A, off);
            s1A += __shfl_xor(s1A, off);
            s0B += __shfl_xor(s0B, off);
            s1B += __shfl_xor(s1B, off);
        }

        float4 advA, advB;
        advA.x = (1.0f - ALPHA) * (qA.x - s0A);
        advA.y = (1.0f - ALPHA) * (qA.y - s0A);
        advA.z = (1.0f - ALPHA) * (qA.z - s0A);
        advA.w = (1.0f - ALPHA) * (qA.w - s0A);
        advB.x = (1.0f - ALPHA) * (qB.x - s0B);
        advB.y = (1.0f - ALPHA) * (qB.y - s0B);
        advB.z = (1.0f - ALPHA) * (qB.z - s0B);
        advB.w = (1.0f - ALPHA) * (qB.w - s0B);
        *(float4*)&adv_out[gA] = advA;
        *(float4*)&adv_out[gB] = advB;

        if (li == 0) {
            sV[lrowA] = s0A;  sVp[lrowA] = s1A;
            sV[lrowB] = s0B;  sVp[lrowB] = s1B;
        }
    }
    __syncthreads();

    // ---- phase C: per-thread coefficients + wave-shuffle suffix scan
    float s0    = sV[tid],  s1 = sVp[tid];
    float kmask = sKm[tid];
    float qa    = sQa[tid];
    float rho   = sRho[tid];
    float est = sRt[tid] + kmask * (GAMMA * s1);
    float td  = est - qa;
    float c   = LAMBD * fminf(fmaxf(rho, 0.0f), 1.0f);
    float Fa  = (LAMBD * GAMMA) * rho * td;    // y_t = Fa + Fb * y_{t+1}
    float Fb  = kmask * (GAMMA * c);
    float E   = est + ALPHA * (qa - s0);       // targets = E + kmask * y_{t+1}

    // inclusive suffix scan within wave (rows wave*64+lane)
    float Ai = Fa, Bi = Fb;
    #pragma unroll
    for (int off = 1; off < 64; off <<= 1) {
        float An = __shfl_down(Ai, off);
        float Bn = __shfl_down(Bi, off);
        if (lane + off < 64) { Ai += Bi * An; Bi *= Bn; }
    }
    if (lane == 0) { sWA[wave] = Ai; sWB[wave] = Bi; }
    // exclusive within wave
    float Xa = __shfl_down(Ai, 1);
    float Xb = __shfl_down(Bi, 1);
    if (lane == 63) { Xa = 0.0f; Xb = 1.0f; }
    __syncthreads();
    if (wave == 0) {                            // append wave 1's composite
        float W1a = sWA[1], W1b = sWB[1];
        Xa = Xa + Xb * W1a;
        Xb = Xb * W1b;
    }
    comb[R0 + tid] = make_float2(E + kmask * Xa, kmask * Xb);
    if (tid == 0) {
        float W1a = sWA[1], W1b = sWB[1];
        cab[blockIdx.x] = make_float2(Ai + Bi * W1a, Bi * W1b);  // full chunk
    }
}

// ---------------------------------------------------------------------------
// K2: each block redundantly suffix-scans nch=2048 chunk composites
// (16 KB, L2-hot): 16-chunk register fold/thread -> 128 supers -> wave scan.
// Thread 0 folds the sub-super tail to get ye for this block, finalize rows.
// ---------------------------------------------------------------------------
__global__ __launch_bounds__(BLK, 8)
void k_fin(const float2* __restrict__ comb, const float2* __restrict__ cab,
           float* __restrict__ targets, int nch)
{
    __shared__ float sXa[BLK], sXb[BLK];
    __shared__ float sWA[2], sWB[2];
    __shared__ float sYe;
    const int tid = threadIdx.x, bid = blockIdx.x;
    const int wave = tid >> 6, lane = tid & 63;

    // fold 16 consecutive chunks (8 float4 loads), outer-first order
    const float4* cab4 = (const float4*)cab;
    float A = 0.0f, B = 1.0f;
    #pragma unroll
    for (int j = 0; j < 8; ++j) {
        float4 u = cab4[tid * 8 + j];
        A += B * u.x; B *= u.y;
        A += B * u.z; B *= u.w;
    }

    // suffix scan over 128 supers: wave shuffle + cross-wave combine
    float Ai = A, Bi = B;
    #pragma unroll
    for (int off = 1; off < 64; off <<= 1) {
        float An = __shfl_down(Ai, off);
        float Bn = __shfl_down(Bi, off);
        if (lane + off < 64) { Ai += Bi * An; Bi *= Bn; }
    }
    if (lane == 0) { sWA[wave] = Ai; sWB[wave] = Bi; }
    float Xa = __shfl_down(Ai, 1);
    float Xb = __shfl_down(Bi, 1);
    if (lane == 63) { Xa = 0.0f; Xb = 1.0f; }
    __syncthreads();
    if (wave == 0) {
        Xa = Xa + Xb * sWA[1];
        Xb = Xb * sWB[1];
    }
    sXa[tid] = Xa; sXb[tid] = Xb;   // exclusive suffix over supers > tid
    __syncthreads();

    if (tid == 0) {
        int c1 = bid + 1;                  // suffix over chunks c1..nch-1
        float ye;
        if (c1 >= nch) {
            ye = 0.0f;
        } else {
            int jq = c1 >> 4, rq = c1 & 15;
            float Aa = sXa[jq], Bb = sXb[jq];     // suffix over supers > jq
            for (int k2 = 16 * jq + 15; k2 >= c1; --k2) {
                float2 cv = cab[k2];
                Aa = cv.x + cv.y * Aa;
                Bb = cv.y * Bb;
            }
            ye = Aa;
        }
        sYe = ye;
    }
    __syncthreads();

    float2 uw = comb[bid * CH + tid];
    targets[bid * CH + tid] = uw.x + uw.y * sYe;
}

extern "C" void kernel_launch(void* const* d_in, const int* in_sizes, int n_in,
                              void* d_out, int out_size, void* d_ws, size_t ws_size,
                              hipStream_t stream) {
    const float* q      = (const float*)d_in[0];
    const float* q_tar  = (const float*)d_in[1];
    const float* pi     = (const float*)d_in[2];
    const int*   a_t    = (const int*)  d_in[3];
    const float* r_t    = (const float*)d_in[4];
    const float* mu_t   = (const float*)d_in[5];
    const int*   done_t = (const int*)  d_in[6];

    const int T   = in_sizes[3];         // 262144
    const int nch = T / CH;              // 2048

    float* targets = (float*)d_out;          // T floats
    float* adv     = (float*)d_out + T;      // T*A floats

    char* ws = (char*)d_ws;
    float2* comb = (float2*)ws;              ws += (size_t)8 * T;
    float2* cab  = (float2*)ws;

    k_main<<<nch, BLK, 0, stream>>>(q, q_tar, pi, a_t, r_t, mu_t, done_t,
                                    adv, comb, cab);
    k_fin<<<nch, BLK, 0, stream>>>(comb, cab, targets, nch);
}